// Round 6
// baseline (441.269 us; speedup 1.0000x reference)
//
#include <hip/hip_runtime.h>
#include <hip/hip_bf16.h>

// KeySelect2 round 6: convm with (kb,r,s) micro-steps, 48 KB LDS -> 3 blocks/CU.
// w: 2 x 8 KB double buffer (one (kb,r,s) chunk), prefetched 1 step ahead.
// x: 2 x 16 KB double buffer (one kb slab), prefetched a full kb ahead.
// One __syncthreads per step; K-split 8 (1024 blocks) fills the 3-slot CUs.
// conv5: same kernel, KQ=1 x 4 splits, atomic into y5 zeroed by localw.

#define B_ 4
#define CM_ 128

typedef __attribute__((ext_vector_type(8))) short short8;
typedef __attribute__((ext_vector_type(4))) float floatx4;
typedef __attribute__((address_space(3))) unsigned lds_as;
typedef __attribute__((address_space(1))) const unsigned glb_as;

__device__ inline short f2bf(float f) {
  union { float f; unsigned u; } v; v.f = f;
  unsigned r = v.u + 0x7fff + ((v.u >> 16) & 1);  // RNE
  return (short)(r >> 16);
}
__device__ inline float bf2f(unsigned short u) {
  union { unsigned u; float f; } v; v.u = ((unsigned)u) << 16;
  return v.f;
}

// ---- x prepack: NCHW fp32 -> [b][kb][row][col][unit^sw][8] bf16 ------------
template <int KB>
__global__ void xprep_kernel(const float* __restrict__ x, short* __restrict__ xt) {
  int kb = blockIdx.x >> 4, rg = blockIdx.x & 15;
  int b = blockIdx.y;
  int row = rg * 4 + (threadIdx.x >> 6);
  int col = threadIdx.x & 63;
  const float* xs = x + (((size_t)b * (KB * 32) + kb * 32) * 64 + row) * 64 + col;
  short* xd = xt + ((((size_t)b * KB + kb) * 64 + row) * 64 + col) * 32;
  int sw = (col >> 1) & 3;
#pragma unroll
  for (int u = 0; u < 4; u++) {
    short8 pk;
#pragma unroll
    for (int j = 0; j < 8; j++) pk[j] = f2bf(xs[(size_t)(u * 8 + j) * 4096]);
    *(short8*)(xd + (u ^ sw) * 8) = pk;
  }
}

// ---- fused prep: xprep(low_key), wfrag 1/4/5, att transpose, zero y1+y4 ----
// wfrag layout: [kb][r(3)][s(3)][m(8)][lane(64)][8] shorts; lane=quad*16+n16
// holds oc=m*16+n16, ic=kb*32+quad*8+j  (MFMA A-fragment order, lane-linear).
__global__ void prep1_kernel(const float* __restrict__ x1,
                             const float* __restrict__ w1, const float* __restrict__ w4,
                             const float* __restrict__ w5, const float* __restrict__ atten,
                             short* __restrict__ xt, short* __restrict__ wf1,
                             short* __restrict__ wf4, short* __restrict__ wf5,
                             float* __restrict__ att_t, float* __restrict__ yz) {
  __shared__ float tile[5184];
  int bx = blockIdx.x, tid = threadIdx.x;
  if (bx < 2048) {  // xprep for low_key
    int b = bx & 3, t = bx >> 2;
    int kb = t >> 4, rg = t & 15;
    int row = rg * 4 + (tid >> 6), col = tid & 63;
    const float* xs = x1 + (((size_t)b * 1024 + kb * 32) * 64 + row) * 64 + col;
    short* xd = xt + ((((size_t)b * 32 + kb) * 64 + row) * 64 + col) * 32;
    int sw = (col >> 1) & 3;
#pragma unroll
    for (int u = 0; u < 4; u++) {
      short8 pk;
#pragma unroll
      for (int j = 0; j < 8; j++) pk[j] = f2bf(xs[(size_t)(u * 8 + j) * 4096]);
      *(short8*)(xd + (u ^ sw) * 8) = pk;
    }
    return;
  }
  bx -= 2048;
  if (bx < 1024) {  // wf1 / wf4 (cin=1024)
    const float* w = bx < 512 ? w1 : w4;
    short* wf = bx < 512 ? wf1 : wf4;
    int idx = (bx & 511) * 256 + tid;
    int oc = idx >> 10, ic = idx & 1023;
    int kb = ic >> 5, icb = ic & 31, quad = icb >> 3, j = icb & 7;
    int m = oc >> 4, n16 = oc & 15, lane = quad * 16 + n16;
    const float* wp = w + ((size_t)oc * 1024 + ic) * 9;
    short* base = wf + (size_t)kb * 36864 + lane * 8 + j;
#pragma unroll
    for (int r = 0; r < 3; r++)
#pragma unroll
      for (int s = 0; s < 3; s++)
        base[(size_t)r * 12288 + (s * 8 + m) * 512] = f2bf(wp[r * 3 + s]);
    return;
  }
  bx -= 1024;
  if (bx < 64) {  // wf5 (cin=128)
    int idx = bx * 256 + tid;
    int oc = idx >> 7, ic = idx & 127;
    int kb = ic >> 5, icb = ic & 31, quad = icb >> 3, j = icb & 7;
    int m = oc >> 4, n16 = oc & 15, lane = quad * 16 + n16;
    const float* wp = w5 + ((size_t)oc * 128 + ic) * 9;
    short* base = wf5 + (size_t)kb * 36864 + lane * 8 + j;
#pragma unroll
    for (int r = 0; r < 3; r++)
#pragma unroll
      for (int s = 0; s < 3; s++)
        base[(size_t)r * 12288 + (s * 8 + m) * 512] = f2bf(wp[r * 3 + s]);
    return;
  }
  bx -= 64;
  if (bx < 256) {  // atten [b,pix,81] -> att_t [b,81,pix]
    int b = bx >> 6;
    int p0 = (bx & 63) * 64;
    const float* src = atten + ((size_t)b * 4096 + p0) * 81;
    for (int e = tid; e < 5184; e += 256) tile[e] = src[e];
    __syncthreads();
    for (int f = tid; f < 5184; f += 256) {
      int k = f >> 6, w_ = f & 63;
      att_t[((size_t)b * 81 + k) * 4096 + p0 + w_] = tile[w_ * 81 + k];
    }
    return;
  }
  bx -= 256;
  // zero y1+y4 (16,777,216 B): 4096 blocks x 256 threads x 16 B
  ((float4*)yz)[(size_t)bx * 256 + tid] = make_float4(0.f, 0.f, 0.f, 0.f);
}

// ---- MFMA conv, (kb,r,s) micro-steps, 48 KB LDS ----------------------------
// grid (128, KSPLIT); block 256 (4 waves). Block tile 128 oc x 128 pix (2 rows).
// wave (mh=wv&1, nh=wv>>1): 64 ocs x one row. Per step: 4 A + 4 B ds_read_b128,
// 16 MFMA. w prefetch 1 step ahead; x prefetch 1 kb ahead. 1 barrier/step.
template <int KQ, bool ATOMIC>
__global__ __launch_bounds__(256, 3)
void convm_kernel(const short* __restrict__ xt, const short* __restrict__ wf,
                  float* __restrict__ yo, int KBtot) {
  __shared__ __attribute__((aligned(16))) short smem[24576];  // 48 KB
  short* sw = smem;          // 2 x 4096 shorts (one (kb,r,s) chunk each)
  short* sx = smem + 8192;   // 2 x 8192 shorts (one kb slab: 4 rows x 64 x 32)
  int tid = threadIdx.x, lane = tid & 63, wv = tid >> 6;
  int n16 = lane & 15, quad = lane >> 4;
  int pg = blockIdx.x;
  int b = pg >> 5, h0 = (pg & 31) * 2;
  int kb0 = blockIdx.y * KQ;
  int mh = wv & 1, nh = wv >> 1;

  // pre-zero boundary x slots in BOTH buffers (never DMA'd)
  if (h0 == 0)
    for (int i = tid; i < 1024; i += 256) { ((int*)sx)[i] = 0; ((int*)(sx + 8192))[i] = 0; }
  if (h0 == 62)
    for (int i = tid; i < 1024; i += 256) {
      ((int*)(sx + 3 * 2048))[i] = 0;
      ((int*)(sx + 8192 + 3 * 2048))[i] = 0;
    }

  auto dma_x = [&](int kbr) {  // kb relative to kb0; buf = kbr&1
    int row = h0 - 1 + wv;     // wave wv stages slot wv
    if (row >= 0 && row < 64) {
      const short* src =
          xt + ((((size_t)b * KBtot + kb0 + kbr) * 64 + row) * 64) * 32 + lane * 8;
      short* dst = sx + (kbr & 1) * 8192 + wv * 2048 + lane * 8;
#pragma unroll
      for (int t = 0; t < 4; t++)
        __builtin_amdgcn_global_load_lds((glb_as*)(src + t * 512), (lds_as*)(dst + t * 512),
                                         16, 0, 0);
    }
  };
  auto dma_w = [&](int step) {  // chunk index kb0*9+step; buf = step&1
    const short* src = wf + ((size_t)(kb0 * 9 + step)) * 4096 + wv * 1024 + lane * 8;
    short* dst = sw + (step & 1) * 4096 + wv * 1024 + lane * 8;
#pragma unroll
    for (int t = 0; t < 2; t++)
      __builtin_amdgcn_global_load_lds((glb_as*)(src + t * 512), (lds_as*)(dst + t * 512),
                                       16, 0, 0);
  };

  floatx4 acc[4][4];
#pragma unroll
  for (int i = 0; i < 4; i++)
#pragma unroll
    for (int n = 0; n < 4; n++) acc[i][n] = (floatx4){0.f, 0.f, 0.f, 0.f};

  dma_x(0);
  dma_w(0);
  const int NS = KQ * 9;
  for (int kb = 0; kb < KQ; kb++) {
#pragma unroll
    for (int rs = 0; rs < 9; rs++) {
      int s = kb * 9 + rs;
      __syncthreads();  // drains DMA issued last step (w) / last kb (x)
      if (s + 1 < NS) dma_w(s + 1);
      if (rs == 0 && kb + 1 < KQ) dma_x(kb + 1);
      int r = rs / 3, sp = rs % 3;  // compile-time after unroll
      const short* swb = sw + (s & 1) * 4096;
      const short* sxr = sx + (kb & 1) * 8192 + (nh + r) * 2048;
      short8 a[4];
#pragma unroll
      for (int i = 0; i < 4; i++)
        a[i] = *(const short8*)(swb + ((mh * 4 + i) * 64 + lane) * 8);
#pragma unroll
      for (int n = 0; n < 4; n++) {
        int c = n * 16 + n16 + sp - 1;  // source col, -1..64
        int cc = c < 0 ? 0 : (c > 63 ? 63 : c);
        short8 bf = *(const short8*)(sxr + cc * 32 + (quad ^ ((cc >> 1) & 3)) * 8);
        if ((n == 0 && sp == 0) || (n == 3 && sp == 2)) {
          short8 zz = {0, 0, 0, 0, 0, 0, 0, 0};
          bf = (c != cc) ? zz : bf;  // zero out-of-image columns
        }
#pragma unroll
        for (int i = 0; i < 4; i++)
          acc[i][n] = __builtin_amdgcn_mfma_f32_16x16x32_bf16(a[i], bf, acc[i][n], 0, 0, 0);
      }
    }
  }

  int row = h0 + nh;
#pragma unroll
  for (int i = 0; i < 4; i++)
#pragma unroll
    for (int n = 0; n < 4; n++)
#pragma unroll
      for (int rg = 0; rg < 4; rg++) {
        int oc = mh * 64 + i * 16 + quad * 4 + rg;  // D: row=quad*4+reg, col=n16
        size_t gi = (((size_t)b * CM_ + oc) * 64 + row) * 64 + n * 16 + n16;
        if (ATOMIC)
          atomicAdd(&yo[gi], acc[i][n][rg]);
        else
          yo[gi] = acc[i][n][rg];
      }
}

// ---- BN stats (pair: by=0 -> set1, by=1 -> set4) ---------------------------
__global__ void bnstats2_kernel(const float* __restrict__ y1, const float* __restrict__ g1,
                                const float* __restrict__ b1, float2* __restrict__ s1,
                                const float* __restrict__ y4, const float* __restrict__ g4,
                                const float* __restrict__ b4, float2* __restrict__ s4) {
  const float* y = blockIdx.y ? y4 : y1;
  const float* g = blockIdx.y ? g4 : g1;
  const float* bt = blockIdx.y ? b4 : b1;
  float2* scsh = blockIdx.y ? s4 : s1;
  int c = blockIdx.x;
  int tid = threadIdx.x;
  float s = 0.f, s2 = 0.f;
  for (int b = 0; b < B_; b++) {
    const float4* p = (const float4*)(y + ((size_t)(b * CM_) + c) * 4096);
    for (int i = tid; i < 1024; i += 256) {
      float4 v = p[i];
      s += v.x + v.y + v.z + v.w;
      s2 += v.x * v.x + v.y * v.y + v.z * v.z + v.w * v.w;
    }
  }
  for (int off = 32; off > 0; off >>= 1) {
    s += __shfl_down(s, off);
    s2 += __shfl_down(s2, off);
  }
  __shared__ float rs[4], rq[4];
  if ((tid & 63) == 0) { rs[tid >> 6] = s; rq[tid >> 6] = s2; }
  __syncthreads();
  if (tid == 0) {
    float S = rs[0] + rs[1] + rs[2] + rs[3];
    float Q = rq[0] + rq[1] + rq[2] + rq[3];
    float mean = S * (1.f / 16384.f);
    float var = Q * (1.f / 16384.f) - mean * mean;
    float sc = g[c] * rsqrtf(var + 1e-5f);
    scsh[c] = make_float2(sc, bt[c] - mean * sc);
  }
}

// ---- BN stats single -------------------------------------------------------
__global__ void bnstats_kernel(const float* __restrict__ y, const float* __restrict__ g,
                               const float* __restrict__ bt, float2* __restrict__ scsh) {
  int c = blockIdx.x;
  int tid = threadIdx.x;
  float s = 0.f, s2 = 0.f;
  for (int b = 0; b < B_; b++) {
    const float4* p = (const float4*)(y + ((size_t)(b * CM_) + c) * 4096);
    for (int i = tid; i < 1024; i += 256) {
      float4 v = p[i];
      s += v.x + v.y + v.z + v.w;
      s2 += v.x * v.x + v.y * v.y + v.z * v.z + v.w * v.w;
    }
  }
  for (int off = 32; off > 0; off >>= 1) {
    s += __shfl_down(s, off);
    s2 += __shfl_down(s2, off);
  }
  __shared__ float rs[4], rq[4];
  if ((tid & 63) == 0) { rs[tid >> 6] = s; rq[tid >> 6] = s2; }
  __syncthreads();
  if (tid == 0) {
    float S = rs[0] + rs[1] + rs[2] + rs[3];
    float Q = rq[0] + rq[1] + rq[2] + rq[3];
    float mean = S * (1.f / 16384.f);
    float var = Q * (1.f / 16384.f) - mean * mean;
    float sc = g[c] * rsqrtf(var + 1e-5f);
    scsh[c] = make_float2(sc, bt[c] - mean * sc);
  }
}

// ---- local weighting + subtract -> xt5; also zeroes y5 ---------------------
// grid (64: b*16+hg (4 rows), 8: cgroup); block 256 (4 waves, 4 ch each).
__global__ __launch_bounds__(256, 2)
void localw_kernel(const float* __restrict__ y1, const float2* __restrict__ scsh1,
                   const float* __restrict__ y4, const float2* __restrict__ scsh4,
                   const float* __restrict__ att_t, short* __restrict__ xt5,
                   float* __restrict__ y5z) {
  __shared__ unsigned short lkb[16][12][72];
  int bx = blockIdx.x;
  int b = bx >> 4, h0 = (bx & 15) * 4;
  int cg = blockIdx.y;
  int tid = threadIdx.x;
  int lane = tid & 63;
  int wv = tid >> 6;

  // zero this block's share of y5 (512 blocks x 256 threads x 4 float4 = 8 MB)
  {
    float4* z = (float4*)y5z;
    int bid = cg * 64 + bx;
#pragma unroll
    for (int t = 0; t < 4; t++)
      z[(size_t)bid * 1024 + t * 256 + tid] = make_float4(0.f, 0.f, 0.f, 0.f);
  }

  for (int e = tid; e < 16 * 12 * 72; e += 256) {
    int c_l = e / (12 * 72);
    int rem = e % (12 * 72);
    int gri = rem / 72, j = rem % 72;
    int row = h0 - 4 + gri, col = j - 4;
    float v = 0.f;
    if (row >= 0 && row < 64 && col >= 0 && col < 64) {
      float2 ss = scsh1[cg * 16 + c_l];
      v = fmaxf(0.f, y1[((size_t)(b * CM_) + cg * 16 + c_l) * 4096 + row * 64 + col] * ss.x + ss.y);
    }
    lkb[c_l][gri][j] = (unsigned short)f2bf(v);
  }
  __syncthreads();

  float acc[4][4];
#pragma unroll
  for (int cc = 0; cc < 4; cc++)
#pragma unroll
    for (int h_i = 0; h_i < 4; h_i++) acc[cc][h_i] = 0.f;

  const float* ab = att_t + (size_t)b * 81 * 4096 + h0 * 64 + lane;

#pragma unroll
  for (int gri = 0; gri < 12; ++gri) {
    float win[4][9];
#pragma unroll
    for (int cc = 0; cc < 4; ++cc)
#pragma unroll
      for (int dw = 0; dw < 9; ++dw)
        win[cc][dw] = bf2f(lkb[wv * 4 + cc][gri][lane + dw]);
#pragma unroll
    for (int h_i = 0; h_i < 4; ++h_i) {
      int r = gri - h_i;
      if (r < 0 || r > 8) continue;
      const float* ap = ab + (size_t)(r * 9) * 4096 + h_i * 64;
      float a[9];
#pragma unroll
      for (int dw = 0; dw < 9; ++dw) a[dw] = ap[(size_t)dw * 4096];
#pragma unroll
      for (int cc = 0; cc < 4; ++cc)
#pragma unroll
        for (int dw = 0; dw < 9; ++dw)
          acc[cc][h_i] = fmaf(a[dw], win[cc][dw], acc[cc][h_i]);
    }
  }

#pragma unroll
  for (int cc = 0; cc < 4; ++cc) {
    int c = cg * 16 + wv * 4 + cc;
    float2 ss4 = scsh4[c];
    int icb = c & 31;
    int uu = (icb >> 3) ^ ((lane >> 1) & 3);
#pragma unroll
    for (int h_i = 0; h_i < 4; ++h_i) {
      int h = h0 + h_i;
      size_t gi = ((size_t)(b * CM_) + c) * 4096 + h * 64 + lane;
      float lnk = fmaxf(0.f, y4[gi] * ss4.x + ss4.y);
      float dv = acc[cc][h_i] - lnk;
      xt5[((((size_t)b * 4 + (c >> 5)) * 64 + h) * 64 + lane) * 32 + uu * 8 + (icb & 7)] =
          f2bf(dv);
    }
  }
}

// ---- global avg pool with BN+ReLU ------------------------------------------
__global__ void pool_kernel(const float* __restrict__ y, const float2* __restrict__ scsh,
                            float* __restrict__ pooled) {
  int bc = blockIdx.x;
  int c = bc & 127;
  float2 ss = scsh[c];
  const float4* p = (const float4*)(y + (size_t)bc * 4096);
  float s = 0.f;
  for (int i = threadIdx.x; i < 1024; i += 256) {
    float4 v = p[i];
    s += fmaxf(0.f, v.x * ss.x + ss.y) + fmaxf(0.f, v.y * ss.x + ss.y) +
         fmaxf(0.f, v.z * ss.x + ss.y) + fmaxf(0.f, v.w * ss.x + ss.y);
  }
  for (int off = 32; off > 0; off >>= 1) s += __shfl_down(s, off);
  __shared__ float rs[4];
  if ((threadIdx.x & 63) == 0) rs[threadIdx.x >> 6] = s;
  __syncthreads();
  if (threadIdx.x == 0) pooled[bc] = (rs[0] + rs[1] + rs[2] + rs[3]) * (1.f / 4096.f);
}

// ---- fc1 + fc2 -------------------------------------------------------------
__global__ void fc_kernel(const float* __restrict__ pooled, const float* __restrict__ fc1w,
                          const float* __restrict__ fc1b, const float* __restrict__ fc2w,
                          const float* __restrict__ fc2b, float* __restrict__ out) {
  int lane = threadIdx.x;
  float p[B_][10];
#pragma unroll
  for (int b = 0; b < B_; b++)
#pragma unroll
    for (int j = 0; j < 10; j++) p[b][j] = 0.f;
  for (int c = lane; c < CM_; c += 64) {
#pragma unroll
    for (int b = 0; b < B_; b++) {
      float pv = pooled[b * CM_ + c];
#pragma unroll
      for (int j = 0; j < 10; j++) p[b][j] = fmaf(pv, fc1w[j * CM_ + c], p[b][j]);
    }
  }
  for (int off = 32; off > 0; off >>= 1)
#pragma unroll
    for (int b = 0; b < B_; b++)
#pragma unroll
      for (int j = 0; j < 10; j++) p[b][j] += __shfl_down(p[b][j], off);
  if (lane == 0) {
    for (int b = 0; b < B_; b++) {
      float o = fc2b[0];
      for (int j = 0; j < 10; j++) o += fc2w[j] * (p[b][j] + fc1b[j]);
      out[b] = o;
    }
  }
}

extern "C" void kernel_launch(void* const* d_in, const int* in_sizes, int n_in,
                              void* d_out, int out_size, void* d_ws, size_t ws_size,
                              hipStream_t stream) {
  const float* low_key    = (const float*)d_in[0];
  const float* low_nonkey = (const float*)d_in[1];
  const float* atten      = (const float*)d_in[2];
  const float* w1  = (const float*)d_in[3];
  const float* g1  = (const float*)d_in[4];
  const float* b1  = (const float*)d_in[5];
  const float* w4  = (const float*)d_in[6];
  const float* g4  = (const float*)d_in[7];
  const float* b4  = (const float*)d_in[8];
  const float* w5  = (const float*)d_in[9];
  const float* g5  = (const float*)d_in[10];
  const float* b5  = (const float*)d_in[11];
  const float* fc1w = (const float*)d_in[12];
  const float* fc1b = (const float*)d_in[13];
  const float* fc2w = (const float*)d_in[14];
  const float* fc2b = (const float*)d_in[15];

  char* w8 = (char*)d_ws;
  short* wf1   = (short*)w8;                       // 2,359,296 B
  short* wf4   = (short*)(w8 + 2359296);           // 2,359,296 B
  short* wf5   = (short*)(w8 + 4718592);           //   294,912 B (pad to 589,824)
  float* att_t = (float*)(w8 + 5308416);           // 5,308,416 B
  short* xt    = (short*)(w8 + 10616832);          // 33,554,432 B
  float* y1    = (float*)(w8 + 44171264);          // 8,388,608 B (zeroed; conv1 acc)
  float* y4    = (float*)(w8 + 52559872);          // 8,388,608 B (zeroed; conv4 acc)
  float2* scsh1 = (float2*)(w8 + 60948480);
  float2* scsh4 = scsh1 + CM_;
  float2* scsh5 = scsh4 + CM_;
  float* pooled = (float*)(scsh5 + CM_);
  short* xt5 = xt;                                  // first 4 MB of dead xt
  float* y5  = (float*)(w8 + 10616832 + 8388608);   // 8 MB inside dead xt, after xt5
  float* out = (float*)d_out;

  // 1. fused prep: xt(low_key), wf1/wf4/wf5 fragment-major, att_t, zero y1+y4
  prep1_kernel<<<7488, 256, 0, stream>>>(low_key, w1, w4, w5, atten,
                                         xt, wf1, wf4, wf5, att_t, y1);
  // 2. conv1: K-split x8, atomic accumulate into zeroed y1
  convm_kernel<4, true><<<dim3(128, 8), 256, 0, stream>>>(xt, wf1, y1, 32);
  // 3. xprep for low_nonkey (reuses xt)
  xprep_kernel<32><<<dim3(512, 4), 256, 0, stream>>>(low_nonkey, xt);
  // 4. conv4
  convm_kernel<4, true><<<dim3(128, 8), 256, 0, stream>>>(xt, wf4, y4, 32);
  // 5. BN stats for conv1 & conv4 in one launch
  bnstats2_kernel<<<dim3(128, 2), 256, 0, stream>>>(y1, g1, b1, scsh1, y4, g4, b4, scsh4);
  // 6. local weighting + subtract -> xt5 (bf16 conv5 layout); zeroes y5
  localw_kernel<<<dim3(64, 8), 256, 0, stream>>>(y1, scsh1, y4, scsh4, att_t, xt5, y5);
  // 7. conv5: K-split x4, atomic into y5
  convm_kernel<1, true><<<dim3(128, 4), 256, 0, stream>>>(xt5, wf5, y5, 4);
  // 8. BN stats for conv5
  bnstats_kernel<<<128, 256, 0, stream>>>(y5, g5, b5, scsh5);
  // 9. pool + 10. fc
  pool_kernel<<<512, 256, 0, stream>>>(y5, scsh5, pooled);
  fc_kernel<<<1, 64, 0, stream>>>(pooled, fc1w, fc1b, fc2w, fc2b, out);
}